// Round 11
// baseline (335.309 us; speedup 1.0000x reference)
//
#include <hip/hip_runtime.h>
#include <hip/hip_bf16.h>

#define BN    4112            // sequence length
#define NKR   4160            // padded key rows: 4048 main + 48 zero-pad + 64 mem
#define BB    2
#define HH    8
#define NIMG_ 4096
#define NMAIN 4048
#define MROWS 8224            // BB*BN
#define VPH   4160            // Vp shorts per hd row: 130 chunks x 32 slots
// (1/sqrt(32)) * log2(e): folded into Q so attention uses raw v_exp_f32 (2^x)
#define QSCALE 0.25505402f

typedef __attribute__((ext_vector_type(8))) short short8;   // 8 bf16 (4 VGPRs)
typedef __attribute__((ext_vector_type(4))) float f32x4;

__device__ __forceinline__ unsigned short f2bs(float x) { return __bfloat16_as_ushort(__float2bfloat16(x)); }
__device__ __forceinline__ unsigned pkbf(float a, float b) {
    __hip_bfloat162 h = __float22bfloat162_rn(make_float2(a, b));   // v_cvt_pk_bf16_f32
    unsigned u; __builtin_memcpy(&u, &h, 4); return u;
}
__device__ __forceinline__ float fexp2(float x) {
#if __has_builtin(__builtin_amdgcn_exp2f)
    return __builtin_amdgcn_exp2f(x);
#else
    return exp2f(x);
#endif
}
__device__ __forceinline__ f32x4 mfma16(short8 a, short8 b, f32x4 c) {
    return __builtin_amdgcn_mfma_f32_16x16x32_bf16(a, b, c, 0, 0, 0);
}

// ---------------- fused QKV projection (one launch) ---------------- (unchanged from R10)
__global__ __launch_bounds__(256)
void qkv_mfma(const float* __restrict__ Aq, const float* __restrict__ Ak, const float* __restrict__ Av,
              const float* __restrict__ Wq, const float* __restrict__ Wk, const float* __restrict__ Wv,
              const float* __restrict__ bq, const float* __restrict__ bk, const float* __restrict__ bv,
              short* __restrict__ Qr, short* __restrict__ Kr, short* __restrict__ Vt,
              const float* __restrict__ fimg, const float* __restrict__ ftxt)
{
    __shared__ __align__(16) short Ws[2][64][72];
    __shared__ __align__(16) short Ds[2][64][72];

    const int mode = blockIdx.z;
    const float* A    = (mode == 0) ? Aq : (mode == 1) ? Ak : Av;
    const float* W    = (mode == 0) ? Wq : (mode == 1) ? Wk : Wv;
    const float* bias = (mode == 0) ? bq : (mode == 1) ? bk : bv;

    const int t    = threadIdx.x;
    const int wave = t >> 6, lane = t & 63, q16 = lane & 15, quad = lane >> 4;
    const int f0 = blockIdx.x * 64;
    const int m0 = blockIdx.y * 64;
    const int sr = t >> 2, sc = (t & 3) * 16;
    const int arow = m0 + sr;
    const bool aval = arow < MROWS;
    const float* wp = W + (size_t)(f0 + sr) * 256 + sc;
    const float* ap = A + (size_t)(aval ? arow : 0) * 256 + sc;

    f32x4 acc[4] = {{0,0,0,0},{0,0,0,0},{0,0,0,0},{0,0,0,0}};

    uint4 wr0, wr1, dr0, dr1;
    {
        float4 a0 = *(const float4*)(wp),     a1 = *(const float4*)(wp + 4);
        float4 a2 = *(const float4*)(wp + 8), a3 = *(const float4*)(wp + 12);
        wr0 = uint4{pkbf(a0.x,a0.y), pkbf(a0.z,a0.w), pkbf(a1.x,a1.y), pkbf(a1.z,a1.w)};
        wr1 = uint4{pkbf(a2.x,a2.y), pkbf(a2.z,a2.w), pkbf(a3.x,a3.y), pkbf(a3.z,a3.w)};
        a0 = *(const float4*)(ap);     a1 = *(const float4*)(ap + 4);
        a2 = *(const float4*)(ap + 8); a3 = *(const float4*)(ap + 12);
        dr0 = uint4{pkbf(a0.x,a0.y), pkbf(a0.z,a0.w), pkbf(a1.x,a1.y), pkbf(a1.z,a1.w)};
        dr1 = uint4{pkbf(a2.x,a2.y), pkbf(a2.z,a2.w), pkbf(a3.x,a3.y), pkbf(a3.z,a3.w)};
    }
    *(uint4*)&Ws[0][sr][sc] = wr0; *(uint4*)&Ws[0][sr][sc + 8] = wr1;
    *(uint4*)&Ds[0][sr][sc] = dr0; *(uint4*)&Ds[0][sr][sc + 8] = dr1;
    __syncthreads();

    #pragma unroll
    for (int ki = 0; ki < 4; ++ki) {
        const int buf = ki & 1;
        if (ki < 3) {
            const int k1 = (ki + 1) * 64;
            float4 a0 = *(const float4*)(wp + k1),     a1 = *(const float4*)(wp + k1 + 4);
            float4 a2 = *(const float4*)(wp + k1 + 8), a3 = *(const float4*)(wp + k1 + 12);
            wr0 = uint4{pkbf(a0.x,a0.y), pkbf(a0.z,a0.w), pkbf(a1.x,a1.y), pkbf(a1.z,a1.w)};
            wr1 = uint4{pkbf(a2.x,a2.y), pkbf(a2.z,a2.w), pkbf(a3.x,a3.y), pkbf(a3.z,a3.w)};
            a0 = *(const float4*)(ap + k1);     a1 = *(const float4*)(ap + k1 + 4);
            a2 = *(const float4*)(ap + k1 + 8); a3 = *(const float4*)(ap + k1 + 12);
            dr0 = uint4{pkbf(a0.x,a0.y), pkbf(a0.z,a0.w), pkbf(a1.x,a1.y), pkbf(a1.z,a1.w)};
            dr1 = uint4{pkbf(a2.x,a2.y), pkbf(a2.z,a2.w), pkbf(a3.x,a3.y), pkbf(a3.z,a3.w)};
        }
        #pragma unroll
        for (int ks = 0; ks < 2; ++ks) {
            const short8 af = *(const short8*)&Ws[buf][wave * 16 + q16][ks * 32 + quad * 8];
            #pragma unroll
            for (int ct = 0; ct < 4; ++ct) {
                const short8 bf = *(const short8*)&Ds[buf][ct * 16 + q16][ks * 32 + quad * 8];
                acc[ct] = mfma16(af, bf, acc[ct]);
            }
        }
        if (ki < 3) {
            *(uint4*)&Ws[buf ^ 1][sr][sc] = wr0; *(uint4*)&Ws[buf ^ 1][sr][sc + 8] = wr1;
            *(uint4*)&Ds[buf ^ 1][sr][sc] = dr0; *(uint4*)&Ds[buf ^ 1][sr][sc + 8] = dr1;
            __syncthreads();
        }
    }

    const int fbase = f0 + wave * 16 + quad * 4;
    const float4 bb = *(const float4*)(bias + fbase);
    float vs[4][4];
    #pragma unroll
    for (int ct = 0; ct < 4; ++ct) {
        int n = m0 + ct * 16 + q16;
        float v0 = acc[ct][0] + bb.x, v1 = acc[ct][1] + bb.y;
        float v2 = acc[ct][2] + bb.z, v3 = acc[ct][3] + bb.w;
        int b  = (n >= BN) ? 1 : 0;
        int nb = n - b * BN;
        if (mode < 2) {
            int j0 = (fbase & 31) >> 1;
            const float* fr = (nb < NIMG_) ? (fimg + ((size_t)nb * 16 + j0) * 2)
                                           : (ftxt + ((size_t)(nb - NIMG_) * 16 + j0) * 2);
            float4 cs = *(const float4*)fr;
            float r0 = v0 * cs.x - v1 * cs.y, i0 = v0 * cs.y + v1 * cs.x;
            float r1 = v2 * cs.z - v3 * cs.w, i1 = v2 * cs.w + v3 * cs.z;
            v0 = r0; v1 = i0; v2 = r1; v3 = i1;
        }
        if (mode == 2) {
            vs[ct][0] = v0; vs[ct][1] = v1; vs[ct][2] = v2; vs[ct][3] = v3;
            continue;
        }
        if (n >= MROWS) continue;
        const int h = (fbase >> 5) & 7, hd = fbase & 31;
        if (mode == 0) {
            unsigned short* op = (unsigned short*)Qr + (((size_t)(b * HH + h) * BN + nb) * 32 + hd);
            *(uint2*)op = uint2{pkbf(v0 * QSCALE, v1 * QSCALE), pkbf(v2 * QSCALE, v3 * QSCALE)};
        } else {
            int nk = nb + ((nb >= NMAIN) ? 48 : 0);
            unsigned short* op = (unsigned short*)Kr + (((size_t)(b * HH + h) * NKR + nk) * 32 + hd);
            *(uint2*)op = uint2{pkbf(v0, v1), pkbf(v2, v3)};
        }
    }

    if (mode == 2) {
        short (*Tr)[72] = Ds[0];
        const int fl = wave * 16 + quad * 4;
        #pragma unroll
        for (int ct = 0; ct < 4; ++ct) {
            const int nl = ct * 16 + q16;
            Tr[fl + 0][nl] = (short)f2bs(vs[ct][0]);
            Tr[fl + 1][nl] = (short)f2bs(vs[ct][1]);
            Tr[fl + 2][nl] = (short)f2bs(vs[ct][2]);
            Tr[fl + 3][nl] = (short)f2bs(vs[ct][3]);
        }
        __syncthreads();
        const int h0 = (f0 >> 5) & 7;
        #pragma unroll
        for (int ii = 0; ii < 2; ++ii) {
            const int r  = ii * 32 + (t >> 3);
            const int c8 = (t & 7) * 8;
            const int ng = m0 + c8;
            if (ng < MROWS) {
                int b  = (ng >= BN) ? 1 : 0;
                int nb = ng - b * BN;
                int h  = h0 + (r >> 5), hd = r & 31;
                size_t hdbase = ((size_t)(b * HH + h) * 32 + hd) * VPH;
                #pragma unroll
                for (int j = 0; j < 2; ++j) {
                    int nb4 = nb + j * 4;
                    int nk  = nb4 + ((nb4 >= NMAIN) ? 48 : 0);
                    int c = nk >> 5, within = nk & 31;
                    int slot = ((within >> 2) & 3) * 8 + ((within >> 4) & 1) * 4;
                    uint2 val = *(const uint2*)&Tr[r][c8 + j * 4];
                    *(uint2*)((unsigned short*)Vt + hdbase + c * 32 + slot) = val;
                }
            }
        }
    }

    if (blockIdx.x == 0 && blockIdx.y < 16) {
        const int bh = blockIdx.y;
        if (mode == 1 && t < 192) {
            short* base = Kr + (size_t)bh * NKR * 32 + (size_t)NMAIN * 32;
            *(uint4*)(base + t * 8) = uint4{0u, 0u, 0u, 0u};
        } else if (mode == 2) {
            for (int i = t; i < 384; i += 256) {
                int hd = i / 12, u = i % 12;
                size_t base = ((size_t)bh * 32 + hd) * VPH;
                int c, slot;
                if (u < 4) { c = 126; slot = 4 + u * 8; }
                else       { c = 127; slot = (u - 4) * 4; }
                *(uint2*)((unsigned short*)Vt + base + c * 32 + slot) = uint2{0u, 0u};
            }
        }
    }
}

// ---------------- barrier-free MFMA flash attention, 4-way key split ----------------
// block = 256 thr = 4 waves over the SAME 32 queries; wave w handles main chunks
// w*32 .. w*32+31 (128 chunks of 32 keys = 4048 main + 48 zero-pads). Wave 3 first computes
// the mem segment (chunks 128,129), normalizes by 1/LB and parks it in LDS. All K/V MFMA
// operands are direct global->reg 16B lane loads (K head-split rows; Vp slot-permuted so the
// PV A-frag is contiguous); P stays in registers (permuted-k PV). Depth-2 two-slot register
// prefetch covers L2 latency. NO in-loop barriers; one end barrier + wave-0 merge.
__global__ __launch_bounds__(256, 5)
void attn_mfma(const short* __restrict__ Qr, const short* __restrict__ Kr,
               const short* __restrict__ Vp, unsigned short* __restrict__ AO)
{
    __shared__ float exO[4][32][36];   // partial O: [wave][q_local][hd] (waves 1..3 write)
    __shared__ float exM[32][36];      // normalized mem contribution
    __shared__ float exL[4][32];       // partial L sums

    const int t = threadIdx.x;
    const int wave = t >> 6, lane = t & 63, q16 = lane & 15, quad = lane >> 4;
    const int bh = blockIdx.y;
    const int qb = blockIdx.x * 32;
    const int q0 = qb + q16, q1 = qb + 16 + q16;
    const int q0c = (q0 < BN) ? q0 : BN - 1;
    const int q1c = (q1 < BN) ? q1 : BN - 1;
    const short8 qf0 = *(const short8*)(Qr + ((size_t)bh * BN + q0c) * 32 + quad * 8);
    const short8 qf1 = *(const short8*)(Qr + ((size_t)bh * BN + q1c) * 32 + quad * 8);

    // wave 3: mem segment first (chunks 128,129); park normalized result in exM
    if (wave == 3) {
        const short* kpm = Kr + (size_t)bh * NKR * 32 + (size_t)4096 * 32 + q16 * 32 + quad * 8;
        const short* vbm = Vp + (size_t)bh * 32 * VPH + 128 * 32 + quad * 8;
        const short* vm0 = vbm + (size_t)q16 * VPH;
        const short* vm1 = vbm + (size_t)(16 + q16) * VPH;
        f32x4 m00 = {0,0,0,0}, m01 = {0,0,0,0}, m10 = {0,0,0,0}, m11 = {0,0,0,0};
        float LB0 = 0.f, LB1 = 0.f;
        #pragma unroll
        for (int g = 0; g < 2; ++g) {
            short8 k0 = *(const short8*)(kpm + g * 1024);
            short8 k1 = *(const short8*)(kpm + g * 1024 + 512);
            short8 v0 = *(const short8*)(vm0 + g * 32);
            short8 v1 = *(const short8*)(vm1 + g * 32);
            const f32x4 z = {0,0,0,0};
            f32x4 s00 = mfma16(k0, qf0, z), s01 = mfma16(k0, qf1, z);
            f32x4 s10 = mfma16(k1, qf0, z), s11 = mfma16(k1, qf1, z);
            float a0 = fexp2(s00[0]), a1 = fexp2(s00[1]), a2 = fexp2(s00[2]), a3 = fexp2(s00[3]);
            float b0 = fexp2(s10[0]), b1 = fexp2(s10[1]), b2 = fexp2(s10[2]), b3 = fexp2(s10[3]);
            float c0 = fexp2(s01[0]), c1 = fexp2(s01[1]), c2 = fexp2(s01[2]), c3 = fexp2(s01[3]);
            float d0 = fexp2(s11[0]), d1 = fexp2(s11[1]), d2 = fexp2(s11[2]), d3 = fexp2(s11[3]);
            LB0 += ((a0 + a1) + (a2 + a3)) + ((b0 + b1) + (b2 + b3));
            LB1 += ((c0 + c1) + (c2 + c3)) + ((d0 + d1) + (d2 + d3));
            uint4 p0u = uint4{pkbf(a0, a1), pkbf(a2, a3), pkbf(b0, b1), pkbf(b2, b3)};
            uint4 p1u = uint4{pkbf(c0, c1), pkbf(c2, c3), pkbf(d0, d1), pkbf(d2, d3)};
            short8 pb0, pb1;
            __builtin_memcpy(&pb0, &p0u, 16); __builtin_memcpy(&pb1, &p1u, 16);
            m00 = mfma16(v0, pb0, m00); m01 = mfma16(v0, pb1, m01);
            m10 = mfma16(v1, pb0, m10); m11 = mfma16(v1, pb1, m11);
        }
        LB0 += __shfl_xor(LB0, 16); LB0 += __shfl_xor(LB0, 32);
        LB1 += __shfl_xor(LB1, 16); LB1 += __shfl_xor(LB1, 32);
        const float iB0 = 1.f / LB0, iB1 = 1.f / LB1;
        #pragma unroll
        for (int r = 0; r < 4; ++r) {
            exM[q16][quad * 4 + r]           = m00[r] * iB0;
            exM[q16][16 + quad * 4 + r]      = m10[r] * iB0;
            exM[16 + q16][quad * 4 + r]      = m01[r] * iB1;
            exM[16 + q16][16 + quad * 4 + r] = m11[r] * iB1;
        }
    }

    // main loop: wave w covers chunks w*32 .. w*32+31
    const short* kp  = Kr + (size_t)bh * NKR * 32 + (size_t)wave * 32 * 1024 + q16 * 32 + quad * 8;
    const short* vb  = Vp + (size_t)bh * 32 * VPH + (size_t)wave * 32 * 32 + quad * 8;
    const short* vp0 = vb + (size_t)q16 * VPH;
    const short* vp1 = vb + (size_t)(16 + q16) * VPH;

    f32x4 o00 = {0,0,0,0}, o01 = {0,0,0,0}, o10 = {0,0,0,0}, o11 = {0,0,0,0};
    float LA0 = 0.f, LA1 = 0.f;

    auto loadc = [&](int g, short8& k0, short8& k1, short8& v0, short8& v1) {
        k0 = *(const short8*)(kp + (size_t)g * 1024);
        k1 = *(const short8*)(kp + (size_t)g * 1024 + 512);
        v0 = *(const short8*)(vp0 + g * 32);
        v1 = *(const short8*)(vp1 + g * 32);
    };
    auto compute = [&](short8 k0, short8 k1, short8 v0, short8 v1) {
        const f32x4 z = {0,0,0,0};
        // query group 0 first, then group 1 (limits live transients)
        f32x4 s00 = mfma16(k0, qf0, z), s10 = mfma16(k1, qf0, z);
        float a0 = fexp2(s00[0]), a1 = fexp2(s00[1]), a2 = fexp2(s00[2]), a3 = fexp2(s00[3]);
        float b0 = fexp2(s10[0]), b1 = fexp2(s10[1]), b2 = fexp2(s10[2]), b3 = fexp2(s10[3]);
        LA0 += ((a0 + a1) + (a2 + a3)) + ((b0 + b1) + (b2 + b3));
        uint4 p0u = uint4{pkbf(a0, a1), pkbf(a2, a3), pkbf(b0, b1), pkbf(b2, b3)};
        short8 pb0; __builtin_memcpy(&pb0, &p0u, 16);
        o00 = mfma16(v0, pb0, o00); o10 = mfma16(v1, pb0, o10);
        f32x4 s01 = mfma16(k0, qf1, z), s11 = mfma16(k1, qf1, z);
        float c0 = fexp2(s01[0]), c1 = fexp2(s01[1]), c2 = fexp2(s01[2]), c3 = fexp2(s01[3]);
        float d0 = fexp2(s11[0]), d1 = fexp2(s11[1]), d2 = fexp2(s11[2]), d3 = fexp2(s11[3]);
        LA1 += ((c0 + c1) + (c2 + c3)) + ((d0 + d1) + (d2 + d3));
        uint4 p1u = uint4{pkbf(c0, c1), pkbf(c2, c3), pkbf(d0, d1), pkbf(d2, d3)};
        short8 pb1; __builtin_memcpy(&pb1, &p1u, 16);
        o01 = mfma16(v0, pb1, o01); o11 = mfma16(v1, pb1, o11);
    };

    short8 ka0, ka1, va0, va1, kb0, kb1, vb0, vb1;
    loadc(0, ka0, ka1, va0, va1);
    loadc(1, kb0, kb1, vb0, vb1);
    #pragma unroll 1
    for (int g = 0; g < 32; g += 2) {
        compute(ka0, ka1, va0, va1);
        if (g + 2 < 32) loadc(g + 2, ka0, ka1, va0, va1);
        compute(kb0, kb1, vb0, vb1);
        if (g + 3 < 32) loadc(g + 3, kb0, kb1, vb0, vb1);
    }

    LA0 += __shfl_xor(LA0, 16); LA0 += __shfl_xor(LA0, 32);
    LA1 += __shfl_xor(LA1, 16); LA1 += __shfl_xor(LA1, 32);

    if (wave != 0) {
        #pragma unroll
        for (int r = 0; r < 4; ++r) {
            exO[wave][q16][quad * 4 + r]           = o00[r];
            exO[wave][q16][16 + quad * 4 + r]      = o10[r];
            exO[wave][16 + q16][quad * 4 + r]      = o01[r];
            exO[wave][16 + q16][16 + quad * 4 + r] = o11[r];
        }
        if (quad == 0) { exL[wave][q16] = LA0; exL[wave][16 + q16] = LA1; }
    }
    __syncthreads();

    if (wave == 0) {
        float LA0t = LA0 - 48.f, LA1t = LA1 - 48.f;   // 48 zero-pad keys: p=1 each
        #pragma unroll
        for (int w2 = 1; w2 < 4; ++w2) {
            o00 += *(const f32x4*)&exO[w2][q16][quad * 4];
            o10 += *(const f32x4*)&exO[w2][q16][16 + quad * 4];
            o01 += *(const f32x4*)&exO[w2][16 + q16][quad * 4];
            o11 += *(const f32x4*)&exO[w2][16 + q16][16 + quad * 4];
            LA0t += exL[w2][q16];
            LA1t += exL[w2][16 + q16];
        }
        const float iA0 = 1.f / LA0t, iA1 = 1.f / LA1t;
        const int b = bh >> 3, h = bh & 7;
        if (q0 < BN) {
            unsigned short* ap = AO + ((size_t)b * BN + q0) * 256 + h * 32;
            float w0[4], w1[4];
            #pragma unroll
            for (int r = 0; r < 4; ++r) {
                w0[r] = o00[r] * iA0 + exM[q16][quad * 4 + r];
                w1[r] = o10[r] * iA0 + exM[q16][16 + quad * 4 + r];
            }
            *(uint2*)(ap + quad * 4)      = uint2{pkbf(w0[0], w0[1]), pkbf(w0[2], w0[3])};
            *(uint2*)(ap + 16 + quad * 4) = uint2{pkbf(w1[0], w1[1]), pkbf(w1[2], w1[3])};
        }
        if (q1 < BN) {
            unsigned short* ap = AO + ((size_t)b * BN + q1) * 256 + h * 32;
            float w0[4], w1[4];
            #pragma unroll
            for (int r = 0; r < 4; ++r) {
                w0[r] = o01[r] * iA1 + exM[16 + q16][quad * 4 + r];
                w1[r] = o11[r] * iA1 + exM[16 + q16][16 + quad * 4 + r];
            }
            *(uint2*)(ap + quad * 4)      = uint2{pkbf(w0[0], w0[1]), pkbf(w0[2], w0[3])};
            *(uint2*)(ap + 16 + quad * 4) = uint2{pkbf(w1[0], w1[1]), pkbf(w1[2], w1[3])};
        }
    }
}

// ---------------- output GEMM ---------------- (unchanged)
__global__ __launch_bounds__(256)
void gemm_out(const unsigned short* __restrict__ A, const float* __restrict__ W,
              const float* __restrict__ bias, float* __restrict__ out)
{
    __shared__ __align__(16) short Ws[2][64][72];
    __shared__ __align__(16) short Ds[2][64][72];
    const int t    = threadIdx.x;
    const int wave = t >> 6, lane = t & 63, q16 = lane & 15, quad = lane >> 4;
    const int f0 = blockIdx.x * 64, m0 = blockIdx.y * 64;
    const int sr = t >> 2, sc = (t & 3) * 16;
    const int arow = m0 + sr;
    const bool aval = arow < MROWS;
    const float* wp = W + (size_t)(f0 + sr) * 256 + sc;
    const unsigned short* ap = A + (size_t)(aval ? arow : 0) * 256 + sc;

    f32x4 acc[4] = {{0,0,0,0},{0,0,0,0},{0,0,0,0},{0,0,0,0}};

    uint4 wr0, wr1, dr0, dr1;
    {
        float4 a0 = *(const float4*)(wp),     a1 = *(const float4*)(wp + 4);
        float4 a2 = *(const float4*)(wp + 8), a3 = *(const float4*)(wp + 12);
        wr0 = uint4{pkbf(a0.x,a0.y), pkbf(a0.z,a0.w), pkbf(a1.x,a1.y), pkbf(a1.z,a1.w)};
        wr1 = uint4{pkbf(a2.x,a2.y), pkbf(a2.z,a2.w), pkbf(a3.x,a3.y), pkbf(a3.z,a3.w)};
        dr0 = *(const uint4*)(ap); dr1 = *(const uint4*)(ap + 8);
    }
    *(uint4*)&Ws[0][sr][sc] = wr0; *(uint4*)&Ws[0][sr][sc + 8] = wr1;
    *(uint4*)&Ds[0][sr][sc] = dr0; *(uint4*)&Ds[0][sr][sc + 8] = dr1;
    __syncthreads();

    #pragma unroll
    for (int ki = 0; ki < 4; ++ki) {
        const int buf = ki & 1;
        if (ki < 3) {
            const int k1 = (ki + 1) * 64;
            float4 a0 = *(const float4*)(wp + k1),     a1 = *(const float4*)(wp + k1 + 4);
            float4 a2 = *(const float4*)(wp + k1 + 8), a3 = *(const float4*)(wp + k1 + 12);
            wr0 = uint4{pkbf(a0.x,a0.y), pkbf(a0.z,a0.w), pkbf(a1.x,a1.y), pkbf(a1.z,a1.w)};
            wr1 = uint4{pkbf(a2.x,a2.y), pkbf(a2.z,a2.w), pkbf(a3.x,a3.y), pkbf(a3.z,a3.w)};
            dr0 = *(const uint4*)(ap + k1); dr1 = *(const uint4*)(ap + k1 + 8);
        }
        #pragma unroll
        for (int ks = 0; ks < 2; ++ks) {
            const short8 af = *(const short8*)&Ws[buf][wave * 16 + q16][ks * 32 + quad * 8];
            #pragma unroll
            for (int ct = 0; ct < 4; ++ct) {
                const short8 bf = *(const short8*)&Ds[buf][ct * 16 + q16][ks * 32 + quad * 8];
                acc[ct] = mfma16(af, bf, acc[ct]);
            }
        }
        if (ki < 3) {
            *(uint4*)&Ws[buf ^ 1][sr][sc] = wr0; *(uint4*)&Ws[buf ^ 1][sr][sc + 8] = wr1;
            *(uint4*)&Ds[buf ^ 1][sr][sc] = dr0; *(uint4*)&Ds[buf ^ 1][sr][sc + 8] = dr1;
            __syncthreads();
        }
    }

    const int fbase = f0 + wave * 16 + quad * 4;
    const float4 bb = *(const float4*)(bias + fbase);
    #pragma unroll
    for (int ct = 0; ct < 4; ++ct) {
        int n = m0 + ct * 16 + q16;
        if (n >= MROWS) continue;
        float* op = out + (size_t)n * 256 + fbase;
        *(float4*)op = float4{acc[ct][0] + bb.x, acc[ct][1] + bb.y,
                              acc[ct][2] + bb.z, acc[ct][3] + bb.w};
    }
}

extern "C" void kernel_launch(void* const* d_in, const int* in_sizes, int n_in,
                              void* d_out, int out_size, void* d_ws, size_t ws_size,
                              hipStream_t stream)
{
    (void)in_sizes; (void)n_in; (void)out_size; (void)ws_size;
    const float* q    = (const float*)d_in[0];
    const float* k    = (const float*)d_in[1];
    const float* v    = (const float*)d_in[2];
    const float* fimg = (const float*)d_in[3];
    const float* ftxt = (const float*)d_in[4];
    const float* Wq   = (const float*)d_in[5];
    const float* bq   = (const float*)d_in[6];
    const float* Wk   = (const float*)d_in[7];
    const float* bk   = (const float*)d_in[8];
    const float* Wv   = (const float*)d_in[9];
    const float* bv   = (const float*)d_in[10];
    const float* Wo   = (const float*)d_in[11];
    const float* bo   = (const float*)d_in[12];
    // d_in[13] = num_k_exclude_rope = 64 (compiled in)

    // workspace: Qr bf16 [16][BN][32]; Kr bf16 [16][NKR][32]; Vp bf16 [16][32][VPH];
    // AO bf16 [BB][BN][256]. Total 16,941,056 B (~16.2 MB)
    char* w = (char*)d_ws;
    short*          Qr = (short*)(w);                    //  4,210,688
    short*          Kr = (short*)(w + 4210688);          //  4,259,840
    short*          Vp = (short*)(w + 8470528);          //  4,259,840
    unsigned short* AO = (unsigned short*)(w + 12730368);//  4,210,688

    qkv_mfma<<<dim3(4, 129, 3), 256, 0, stream>>>(q, k, v, Wq, Wk, Wv, bq, bk, bv,
                                                  Qr, Kr, Vp, fimg, ftxt);
    attn_mfma<<<dim3(129, 16), 256, 0, stream>>>(Qr, Kr, Vp, AO);
    gemm_out<<<dim3(4, 129), 256, 0, stream>>>(AO, Wo, bo, (float*)d_out);
}

// Round 12
// 218.459 us; speedup vs baseline: 1.5349x; 1.5349x over previous
//
#include <hip/hip_runtime.h>
#include <hip/hip_bf16.h>

#define BN    4112            // sequence length
#define NKR   4160            // padded key rows: 4048 main + 48 zero-pad + 64 mem
#define BB    2
#define HH    8
#define NIMG_ 4096
#define NMAIN 4048
#define MROWS 8224            // BB*BN
#define VPH   4160            // Vp shorts per hd row: 130 chunks x 32 slots
// (1/sqrt(32)) * log2(e): folded into Q so attention uses raw v_exp_f32 (2^x)
#define QSCALE 0.25505402f

typedef __attribute__((ext_vector_type(8))) short short8;   // 8 bf16 (4 VGPRs)
typedef __attribute__((ext_vector_type(4))) float f32x4;

__device__ __forceinline__ unsigned short f2bs(float x) { return __bfloat16_as_ushort(__float2bfloat16(x)); }
__device__ __forceinline__ unsigned pkbf(float a, float b) {
    __hip_bfloat162 h = __float22bfloat162_rn(make_float2(a, b));   // v_cvt_pk_bf16_f32
    unsigned u; __builtin_memcpy(&u, &h, 4); return u;
}
__device__ __forceinline__ float fexp2(float x) {
#if __has_builtin(__builtin_amdgcn_exp2f)
    return __builtin_amdgcn_exp2f(x);
#else
    return exp2f(x);
#endif
}
__device__ __forceinline__ f32x4 mfma16(short8 a, short8 b, f32x4 c) {
    return __builtin_amdgcn_mfma_f32_16x16x32_bf16(a, b, c, 0, 0, 0);
}

// ---------------- fused QKV projection (one launch) ---------------- (unchanged)
__global__ __launch_bounds__(256)
void qkv_mfma(const float* __restrict__ Aq, const float* __restrict__ Ak, const float* __restrict__ Av,
              const float* __restrict__ Wq, const float* __restrict__ Wk, const float* __restrict__ Wv,
              const float* __restrict__ bq, const float* __restrict__ bk, const float* __restrict__ bv,
              short* __restrict__ Qr, short* __restrict__ Kr, short* __restrict__ Vt,
              const float* __restrict__ fimg, const float* __restrict__ ftxt)
{
    __shared__ __align__(16) short Ws[2][64][72];
    __shared__ __align__(16) short Ds[2][64][72];

    const int mode = blockIdx.z;
    const float* A    = (mode == 0) ? Aq : (mode == 1) ? Ak : Av;
    const float* W    = (mode == 0) ? Wq : (mode == 1) ? Wk : Wv;
    const float* bias = (mode == 0) ? bq : (mode == 1) ? bk : bv;

    const int t    = threadIdx.x;
    const int wave = t >> 6, lane = t & 63, q16 = lane & 15, quad = lane >> 4;
    const int f0 = blockIdx.x * 64;
    const int m0 = blockIdx.y * 64;
    const int sr = t >> 2, sc = (t & 3) * 16;
    const int arow = m0 + sr;
    const bool aval = arow < MROWS;
    const float* wp = W + (size_t)(f0 + sr) * 256 + sc;
    const float* ap = A + (size_t)(aval ? arow : 0) * 256 + sc;

    f32x4 acc[4] = {{0,0,0,0},{0,0,0,0},{0,0,0,0},{0,0,0,0}};

    uint4 wr0, wr1, dr0, dr1;
    {
        float4 a0 = *(const float4*)(wp),     a1 = *(const float4*)(wp + 4);
        float4 a2 = *(const float4*)(wp + 8), a3 = *(const float4*)(wp + 12);
        wr0 = uint4{pkbf(a0.x,a0.y), pkbf(a0.z,a0.w), pkbf(a1.x,a1.y), pkbf(a1.z,a1.w)};
        wr1 = uint4{pkbf(a2.x,a2.y), pkbf(a2.z,a2.w), pkbf(a3.x,a3.y), pkbf(a3.z,a3.w)};
        a0 = *(const float4*)(ap);     a1 = *(const float4*)(ap + 4);
        a2 = *(const float4*)(ap + 8); a3 = *(const float4*)(ap + 12);
        dr0 = uint4{pkbf(a0.x,a0.y), pkbf(a0.z,a0.w), pkbf(a1.x,a1.y), pkbf(a1.z,a1.w)};
        dr1 = uint4{pkbf(a2.x,a2.y), pkbf(a2.z,a2.w), pkbf(a3.x,a3.y), pkbf(a3.z,a3.w)};
    }
    *(uint4*)&Ws[0][sr][sc] = wr0; *(uint4*)&Ws[0][sr][sc + 8] = wr1;
    *(uint4*)&Ds[0][sr][sc] = dr0; *(uint4*)&Ds[0][sr][sc + 8] = dr1;
    __syncthreads();

    #pragma unroll
    for (int ki = 0; ki < 4; ++ki) {
        const int buf = ki & 1;
        if (ki < 3) {
            const int k1 = (ki + 1) * 64;
            float4 a0 = *(const float4*)(wp + k1),     a1 = *(const float4*)(wp + k1 + 4);
            float4 a2 = *(const float4*)(wp + k1 + 8), a3 = *(const float4*)(wp + k1 + 12);
            wr0 = uint4{pkbf(a0.x,a0.y), pkbf(a0.z,a0.w), pkbf(a1.x,a1.y), pkbf(a1.z,a1.w)};
            wr1 = uint4{pkbf(a2.x,a2.y), pkbf(a2.z,a2.w), pkbf(a3.x,a3.y), pkbf(a3.z,a3.w)};
            a0 = *(const float4*)(ap + k1);     a1 = *(const float4*)(ap + k1 + 4);
            a2 = *(const float4*)(ap + k1 + 8); a3 = *(const float4*)(ap + k1 + 12);
            dr0 = uint4{pkbf(a0.x,a0.y), pkbf(a0.z,a0.w), pkbf(a1.x,a1.y), pkbf(a1.z,a1.w)};
            dr1 = uint4{pkbf(a2.x,a2.y), pkbf(a2.z,a2.w), pkbf(a3.x,a3.y), pkbf(a3.z,a3.w)};
        }
        #pragma unroll
        for (int ks = 0; ks < 2; ++ks) {
            const short8 af = *(const short8*)&Ws[buf][wave * 16 + q16][ks * 32 + quad * 8];
            #pragma unroll
            for (int ct = 0; ct < 4; ++ct) {
                const short8 bf = *(const short8*)&Ds[buf][ct * 16 + q16][ks * 32 + quad * 8];
                acc[ct] = mfma16(af, bf, acc[ct]);
            }
        }
        if (ki < 3) {
            *(uint4*)&Ws[buf ^ 1][sr][sc] = wr0; *(uint4*)&Ws[buf ^ 1][sr][sc + 8] = wr1;
            *(uint4*)&Ds[buf ^ 1][sr][sc] = dr0; *(uint4*)&Ds[buf ^ 1][sr][sc + 8] = dr1;
            __syncthreads();
        }
    }

    const int fbase = f0 + wave * 16 + quad * 4;
    const float4 bb = *(const float4*)(bias + fbase);
    float vs[4][4];
    #pragma unroll
    for (int ct = 0; ct < 4; ++ct) {
        int n = m0 + ct * 16 + q16;
        float v0 = acc[ct][0] + bb.x, v1 = acc[ct][1] + bb.y;
        float v2 = acc[ct][2] + bb.z, v3 = acc[ct][3] + bb.w;
        int b  = (n >= BN) ? 1 : 0;
        int nb = n - b * BN;
        if (mode < 2) {
            int j0 = (fbase & 31) >> 1;
            const float* fr = (nb < NIMG_) ? (fimg + ((size_t)nb * 16 + j0) * 2)
                                           : (ftxt + ((size_t)(nb - NIMG_) * 16 + j0) * 2);
            float4 cs = *(const float4*)fr;
            float r0 = v0 * cs.x - v1 * cs.y, i0 = v0 * cs.y + v1 * cs.x;
            float r1 = v2 * cs.z - v3 * cs.w, i1 = v2 * cs.w + v3 * cs.z;
            v0 = r0; v1 = i0; v2 = r1; v3 = i1;
        }
        if (mode == 2) {
            vs[ct][0] = v0; vs[ct][1] = v1; vs[ct][2] = v2; vs[ct][3] = v3;
            continue;
        }
        if (n >= MROWS) continue;
        const int h = (fbase >> 5) & 7, hd = fbase & 31;
        if (mode == 0) {
            unsigned short* op = (unsigned short*)Qr + (((size_t)(b * HH + h) * BN + nb) * 32 + hd);
            *(uint2*)op = uint2{pkbf(v0 * QSCALE, v1 * QSCALE), pkbf(v2 * QSCALE, v3 * QSCALE)};
        } else {
            int nk = nb + ((nb >= NMAIN) ? 48 : 0);
            unsigned short* op = (unsigned short*)Kr + (((size_t)(b * HH + h) * NKR + nk) * 32 + hd);
            *(uint2*)op = uint2{pkbf(v0, v1), pkbf(v2, v3)};
        }
    }

    if (mode == 2) {
        short (*Tr)[72] = Ds[0];
        const int fl = wave * 16 + quad * 4;
        #pragma unroll
        for (int ct = 0; ct < 4; ++ct) {
            const int nl = ct * 16 + q16;
            Tr[fl + 0][nl] = (short)f2bs(vs[ct][0]);
            Tr[fl + 1][nl] = (short)f2bs(vs[ct][1]);
            Tr[fl + 2][nl] = (short)f2bs(vs[ct][2]);
            Tr[fl + 3][nl] = (short)f2bs(vs[ct][3]);
        }
        __syncthreads();
        const int h0 = (f0 >> 5) & 7;
        #pragma unroll
        for (int ii = 0; ii < 2; ++ii) {
            const int r  = ii * 32 + (t >> 3);
            const int c8 = (t & 7) * 8;
            const int ng = m0 + c8;
            if (ng < MROWS) {
                int b  = (ng >= BN) ? 1 : 0;
                int nb = ng - b * BN;
                int h  = h0 + (r >> 5), hd = r & 31;
                size_t hdbase = ((size_t)(b * HH + h) * 32 + hd) * VPH;
                #pragma unroll
                for (int j = 0; j < 2; ++j) {
                    int nb4 = nb + j * 4;
                    int nk  = nb4 + ((nb4 >= NMAIN) ? 48 : 0);
                    int c = nk >> 5, within = nk & 31;
                    int slot = ((within >> 2) & 3) * 8 + ((within >> 4) & 1) * 4;
                    uint2 val = *(const uint2*)&Tr[r][c8 + j * 4];
                    *(uint2*)((unsigned short*)Vt + hdbase + c * 32 + slot) = val;
                }
            }
        }
    }

    if (blockIdx.x == 0 && blockIdx.y < 16) {
        const int bh = blockIdx.y;
        if (mode == 1 && t < 192) {
            short* base = Kr + (size_t)bh * NKR * 32 + (size_t)NMAIN * 32;
            *(uint4*)(base + t * 8) = uint4{0u, 0u, 0u, 0u};
        } else if (mode == 2) {
            for (int i = t; i < 384; i += 256) {
                int hd = i / 12, u = i % 12;
                size_t base = ((size_t)bh * 32 + hd) * VPH;
                int c, slot;
                if (u < 4) { c = 126; slot = 4 + u * 8; }
                else       { c = 127; slot = (u - 4) * 4; }
                *(uint2*)((unsigned short*)Vt + base + c * 32 + slot) = uint2{0u, 0u};
            }
        }
    }
}

// ---------------- barrier-free MFMA flash attention, 4-way key split ----------------
// Identical structure to R11; ONLY change: __launch_bounds__(256, 4) so the ~90-VGPR live
// set (2x4 short8 prefetch slots + 4 f32x4 accums + 2 Q frags + transients) fits without
// scratch spill (R11's (256,5) cap caused 379 MB of spill traffic -> HBM-bound).
__global__ __launch_bounds__(256, 4)
void attn_mfma(const short* __restrict__ Qr, const short* __restrict__ Kr,
               const short* __restrict__ Vp, unsigned short* __restrict__ AO)
{
    __shared__ float exO[4][32][36];   // partial O: [wave][q_local][hd] (waves 1..3 write)
    __shared__ float exM[32][36];      // normalized mem contribution
    __shared__ float exL[4][32];       // partial L sums

    const int t = threadIdx.x;
    const int wave = t >> 6, lane = t & 63, q16 = lane & 15, quad = lane >> 4;
    const int bh = blockIdx.y;
    const int qb = blockIdx.x * 32;
    const int q0 = qb + q16, q1 = qb + 16 + q16;
    const int q0c = (q0 < BN) ? q0 : BN - 1;
    const int q1c = (q1 < BN) ? q1 : BN - 1;
    const short8 qf0 = *(const short8*)(Qr + ((size_t)bh * BN + q0c) * 32 + quad * 8);
    const short8 qf1 = *(const short8*)(Qr + ((size_t)bh * BN + q1c) * 32 + quad * 8);

    // wave 3: mem segment first (chunks 128,129); park normalized result in exM
    if (wave == 3) {
        const short* kpm = Kr + (size_t)bh * NKR * 32 + (size_t)4096 * 32 + q16 * 32 + quad * 8;
        const short* vbm = Vp + (size_t)bh * 32 * VPH + 128 * 32 + quad * 8;
        const short* vm0 = vbm + (size_t)q16 * VPH;
        const short* vm1 = vbm + (size_t)(16 + q16) * VPH;
        f32x4 m00 = {0,0,0,0}, m01 = {0,0,0,0}, m10 = {0,0,0,0}, m11 = {0,0,0,0};
        float LB0 = 0.f, LB1 = 0.f;
        #pragma unroll
        for (int g = 0; g < 2; ++g) {
            short8 k0 = *(const short8*)(kpm + g * 1024);
            short8 k1 = *(const short8*)(kpm + g * 1024 + 512);
            short8 v0 = *(const short8*)(vm0 + g * 32);
            short8 v1 = *(const short8*)(vm1 + g * 32);
            const f32x4 z = {0,0,0,0};
            f32x4 s00 = mfma16(k0, qf0, z), s01 = mfma16(k0, qf1, z);
            f32x4 s10 = mfma16(k1, qf0, z), s11 = mfma16(k1, qf1, z);
            float a0 = fexp2(s00[0]), a1 = fexp2(s00[1]), a2 = fexp2(s00[2]), a3 = fexp2(s00[3]);
            float b0 = fexp2(s10[0]), b1 = fexp2(s10[1]), b2 = fexp2(s10[2]), b3 = fexp2(s10[3]);
            float c0 = fexp2(s01[0]), c1 = fexp2(s01[1]), c2 = fexp2(s01[2]), c3 = fexp2(s01[3]);
            float d0 = fexp2(s11[0]), d1 = fexp2(s11[1]), d2 = fexp2(s11[2]), d3 = fexp2(s11[3]);
            LB0 += ((a0 + a1) + (a2 + a3)) + ((b0 + b1) + (b2 + b3));
            LB1 += ((c0 + c1) + (c2 + c3)) + ((d0 + d1) + (d2 + d3));
            uint4 p0u = uint4{pkbf(a0, a1), pkbf(a2, a3), pkbf(b0, b1), pkbf(b2, b3)};
            uint4 p1u = uint4{pkbf(c0, c1), pkbf(c2, c3), pkbf(d0, d1), pkbf(d2, d3)};
            short8 pb0, pb1;
            __builtin_memcpy(&pb0, &p0u, 16); __builtin_memcpy(&pb1, &p1u, 16);
            m00 = mfma16(v0, pb0, m00); m01 = mfma16(v0, pb1, m01);
            m10 = mfma16(v1, pb0, m10); m11 = mfma16(v1, pb1, m11);
        }
        LB0 += __shfl_xor(LB0, 16); LB0 += __shfl_xor(LB0, 32);
        LB1 += __shfl_xor(LB1, 16); LB1 += __shfl_xor(LB1, 32);
        const float iB0 = 1.f / LB0, iB1 = 1.f / LB1;
        #pragma unroll
        for (int r = 0; r < 4; ++r) {
            exM[q16][quad * 4 + r]           = m00[r] * iB0;
            exM[q16][16 + quad * 4 + r]      = m10[r] * iB0;
            exM[16 + q16][quad * 4 + r]      = m01[r] * iB1;
            exM[16 + q16][16 + quad * 4 + r] = m11[r] * iB1;
        }
    }

    // main loop: wave w covers chunks w*32 .. w*32+31
    const short* kp  = Kr + (size_t)bh * NKR * 32 + (size_t)wave * 32 * 1024 + q16 * 32 + quad * 8;
    const short* vb  = Vp + (size_t)bh * 32 * VPH + (size_t)wave * 32 * 32 + quad * 8;
    const short* vp0 = vb + (size_t)q16 * VPH;
    const short* vp1 = vb + (size_t)(16 + q16) * VPH;

    f32x4 o00 = {0,0,0,0}, o01 = {0,0,0,0}, o10 = {0,0,0,0}, o11 = {0,0,0,0};
    float LA0 = 0.f, LA1 = 0.f;

    auto loadc = [&](int g, short8& k0, short8& k1, short8& v0, short8& v1) {
        k0 = *(const short8*)(kp + (size_t)g * 1024);
        k1 = *(const short8*)(kp + (size_t)g * 1024 + 512);
        v0 = *(const short8*)(vp0 + g * 32);
        v1 = *(const short8*)(vp1 + g * 32);
    };
    auto compute = [&](short8 k0, short8 k1, short8 v0, short8 v1) {
        const f32x4 z = {0,0,0,0};
        f32x4 s00 = mfma16(k0, qf0, z), s10 = mfma16(k1, qf0, z);
        float a0 = fexp2(s00[0]), a1 = fexp2(s00[1]), a2 = fexp2(s00[2]), a3 = fexp2(s00[3]);
        float b0 = fexp2(s10[0]), b1 = fexp2(s10[1]), b2 = fexp2(s10[2]), b3 = fexp2(s10[3]);
        LA0 += ((a0 + a1) + (a2 + a3)) + ((b0 + b1) + (b2 + b3));
        uint4 p0u = uint4{pkbf(a0, a1), pkbf(a2, a3), pkbf(b0, b1), pkbf(b2, b3)};
        short8 pb0; __builtin_memcpy(&pb0, &p0u, 16);
        o00 = mfma16(v0, pb0, o00); o10 = mfma16(v1, pb0, o10);
        f32x4 s01 = mfma16(k0, qf1, z), s11 = mfma16(k1, qf1, z);
        float c0 = fexp2(s01[0]), c1 = fexp2(s01[1]), c2 = fexp2(s01[2]), c3 = fexp2(s01[3]);
        float d0 = fexp2(s11[0]), d1 = fexp2(s11[1]), d2 = fexp2(s11[2]), d3 = fexp2(s11[3]);
        LA1 += ((c0 + c1) + (c2 + c3)) + ((d0 + d1) + (d2 + d3));
        uint4 p1u = uint4{pkbf(c0, c1), pkbf(c2, c3), pkbf(d0, d1), pkbf(d2, d3)};
        short8 pb1; __builtin_memcpy(&pb1, &p1u, 16);
        o01 = mfma16(v0, pb1, o01); o11 = mfma16(v1, pb1, o11);
    };

    short8 ka0, ka1, va0, va1, kb0, kb1, vb0, vb1;
    loadc(0, ka0, ka1, va0, va1);
    loadc(1, kb0, kb1, vb0, vb1);
    #pragma unroll 1
    for (int g = 0; g < 32; g += 2) {
        compute(ka0, ka1, va0, va1);
        if (g + 2 < 32) loadc(g + 2, ka0, ka1, va0, va1);
        compute(kb0, kb1, vb0, vb1);
        if (g + 3 < 32) loadc(g + 3, kb0, kb1, vb0, vb1);
    }

    LA0 += __shfl_xor(LA0, 16); LA0 += __shfl_xor(LA0, 32);
    LA1 += __shfl_xor(LA1, 16); LA1 += __shfl_xor(LA1, 32);

    if (wave != 0) {
        #pragma unroll
        for (int r = 0; r < 4; ++r) {
            exO[wave][q16][quad * 4 + r]           = o00[r];
            exO[wave][q16][16 + quad * 4 + r]      = o10[r];
            exO[wave][16 + q16][quad * 4 + r]      = o01[r];
            exO[wave][16 + q16][16 + quad * 4 + r] = o11[r];
        }
        if (quad == 0) { exL[wave][q16] = LA0; exL[wave][16 + q16] = LA1; }
    }
    __syncthreads();

    if (wave == 0) {
        float LA0t = LA0 - 48.f, LA1t = LA1 - 48.f;   // 48 zero-pad keys: p=1 each
        #pragma unroll
        for (int w2 = 1; w2 < 4; ++w2) {
            o00 += *(const f32x4*)&exO[w2][q16][quad * 4];
            o10 += *(const f32x4*)&exO[w2][q16][16 + quad * 4];
            o01 += *(const f32x4*)&exO[w2][16 + q16][quad * 4];
            o11 += *(const f32x4*)&exO[w2][16 + q16][16 + quad * 4];
            LA0t += exL[w2][q16];
            LA1t += exL[w2][16 + q16];
        }
        const float iA0 = 1.f / LA0t, iA1 = 1.f / LA1t;
        const int b = bh >> 3, h = bh & 7;
        if (q0 < BN) {
            unsigned short* ap = AO + ((size_t)b * BN + q0) * 256 + h * 32;
            float w0[4], w1[4];
            #pragma unroll
            for (int r = 0; r < 4; ++r) {
                w0[r] = o00[r] * iA0 + exM[q16][quad * 4 + r];
                w1[r] = o10[r] * iA0 + exM[q16][16 + quad * 4 + r];
            }
            *(uint2*)(ap + quad * 4)      = uint2{pkbf(w0[0], w0[1]), pkbf(w0[2], w0[3])};
            *(uint2*)(ap + 16 + quad * 4) = uint2{pkbf(w1[0], w1[1]), pkbf(w1[2], w1[3])};
        }
        if (q1 < BN) {
            unsigned short* ap = AO + ((size_t)b * BN + q1) * 256 + h * 32;
            float w0[4], w1[4];
            #pragma unroll
            for (int r = 0; r < 4; ++r) {
                w0[r] = o01[r] * iA1 + exM[16 + q16][quad * 4 + r];
                w1[r] = o11[r] * iA1 + exM[16 + q16][16 + quad * 4 + r];
            }
            *(uint2*)(ap + quad * 4)      = uint2{pkbf(w0[0], w0[1]), pkbf(w0[2], w0[3])};
            *(uint2*)(ap + 16 + quad * 4) = uint2{pkbf(w1[0], w1[1]), pkbf(w1[2], w1[3])};
        }
    }
}

// ---------------- output GEMM ---------------- (unchanged)
__global__ __launch_bounds__(256)
void gemm_out(const unsigned short* __restrict__ A, const float* __restrict__ W,
              const float* __restrict__ bias, float* __restrict__ out)
{
    __shared__ __align__(16) short Ws[2][64][72];
    __shared__ __align__(16) short Ds[2][64][72];
    const int t    = threadIdx.x;
    const int wave = t >> 6, lane = t & 63, q16 = lane & 15, quad = lane >> 4;
    const int f0 = blockIdx.x * 64, m0 = blockIdx.y * 64;
    const int sr = t >> 2, sc = (t & 3) * 16;
    const int arow = m0 + sr;
    const bool aval = arow < MROWS;
    const float* wp = W + (size_t)(f0 + sr) * 256 + sc;
    const unsigned short* ap = A + (size_t)(aval ? arow : 0) * 256 + sc;

    f32x4 acc[4] = {{0,0,0,0},{0,0,0,0},{0,0,0,0},{0,0,0,0}};

    uint4 wr0, wr1, dr0, dr1;
    {
        float4 a0 = *(const float4*)(wp),     a1 = *(const float4*)(wp + 4);
        float4 a2 = *(const float4*)(wp + 8), a3 = *(const float4*)(wp + 12);
        wr0 = uint4{pkbf(a0.x,a0.y), pkbf(a0.z,a0.w), pkbf(a1.x,a1.y), pkbf(a1.z,a1.w)};
        wr1 = uint4{pkbf(a2.x,a2.y), pkbf(a2.z,a2.w), pkbf(a3.x,a3.y), pkbf(a3.z,a3.w)};
        dr0 = *(const uint4*)(ap); dr1 = *(const uint4*)(ap + 8);
    }
    *(uint4*)&Ws[0][sr][sc] = wr0; *(uint4*)&Ws[0][sr][sc + 8] = wr1;
    *(uint4*)&Ds[0][sr][sc] = dr0; *(uint4*)&Ds[0][sr][sc + 8] = dr1;
    __syncthreads();

    #pragma unroll
    for (int ki = 0; ki < 4; ++ki) {
        const int buf = ki & 1;
        if (ki < 3) {
            const int k1 = (ki + 1) * 64;
            float4 a0 = *(const float4*)(wp + k1),     a1 = *(const float4*)(wp + k1 + 4);
            float4 a2 = *(const float4*)(wp + k1 + 8), a3 = *(const float4*)(wp + k1 + 12);
            wr0 = uint4{pkbf(a0.x,a0.y), pkbf(a0.z,a0.w), pkbf(a1.x,a1.y), pkbf(a1.z,a1.w)};
            wr1 = uint4{pkbf(a2.x,a2.y), pkbf(a2.z,a2.w), pkbf(a3.x,a3.y), pkbf(a3.z,a3.w)};
            dr0 = *(const uint4*)(ap + k1); dr1 = *(const uint4*)(ap + k1 + 8);
        }
        #pragma unroll
        for (int ks = 0; ks < 2; ++ks) {
            const short8 af = *(const short8*)&Ws[buf][wave * 16 + q16][ks * 32 + quad * 8];
            #pragma unroll
            for (int ct = 0; ct < 4; ++ct) {
                const short8 bf = *(const short8*)&Ds[buf][ct * 16 + q16][ks * 32 + quad * 8];
                acc[ct] = mfma16(af, bf, acc[ct]);
            }
        }
        if (ki < 3) {
            *(uint4*)&Ws[buf ^ 1][sr][sc] = wr0; *(uint4*)&Ws[buf ^ 1][sr][sc + 8] = wr1;
            *(uint4*)&Ds[buf ^ 1][sr][sc] = dr0; *(uint4*)&Ds[buf ^ 1][sr][sc + 8] = dr1;
            __syncthreads();
        }
    }

    const int fbase = f0 + wave * 16 + quad * 4;
    const float4 bb = *(const float4*)(bias + fbase);
    #pragma unroll
    for (int ct = 0; ct < 4; ++ct) {
        int n = m0 + ct * 16 + q16;
        if (n >= MROWS) continue;
        float* op = out + (size_t)n * 256 + fbase;
        *(float4*)op = float4{acc[ct][0] + bb.x, acc[ct][1] + bb.y,
                              acc[ct][2] + bb.z, acc[ct][3] + bb.w};
    }
}

extern "C" void kernel_launch(void* const* d_in, const int* in_sizes, int n_in,
                              void* d_out, int out_size, void* d_ws, size_t ws_size,
                              hipStream_t stream)
{
    (void)in_sizes; (void)n_in; (void)out_size; (void)ws_size;
    const float* q    = (const float*)d_in[0];
    const float* k    = (const float*)d_in[1];
    const float* v    = (const float*)d_in[2];
    const float* fimg = (const float*)d_in[3];
    const float* ftxt = (const float*)d_in[4];
    const float* Wq   = (const float*)d_in[5];
    const float* bq   = (const float*)d_in[6];
    const float* Wk   = (const float*)d_in[7];
    const float* bk   = (const float*)d_in[8];
    const float* Wv   = (const float*)d_in[9];
    const float* bv   = (const float*)d_in[10];
    const float* Wo   = (const float*)d_in[11];
    const float* bo   = (const float*)d_in[12];
    // d_in[13] = num_k_exclude_rope = 64 (compiled in)

    // workspace: Qr bf16 [16][BN][32]; Kr bf16 [16][NKR][32]; Vp bf16 [16][32][VPH];
    // AO bf16 [BB][BN][256]. Total 16,941,056 B (~16.2 MB)
    char* w = (char*)d_ws;
    short*          Qr = (short*)(w);                    //  4,210,688
    short*          Kr = (short*)(w + 4210688);          //  4,259,840
    short*          Vp = (short*)(w + 8470528);          //  4,259,840
    unsigned short* AO = (unsigned short*)(w + 12730368);//  4,210,688

    qkv_mfma<<<dim3(4, 129, 3), 256, 0, stream>>>(q, k, v, Wq, Wk, Wv, bq, bk, bv,
                                                  Qr, Kr, Vp, fimg, ftxt);
    attn_mfma<<<dim3(129, 16), 256, 0, stream>>>(Qr, Kr, Vp, AO);
    gemm_out<<<dim3(4, 129), 256, 0, stream>>>(AO, Wo, bo, (float*)d_out);
}